// Round 1
// baseline (1564.969 us; speedup 1.0000x reference)
//
#include <hip/hip_runtime.h>
#include <hip/hip_fp16.h>
#include <cstdint>

#define T_LEN 128
#define DA    16
#define DZ    32
#define HH    128

__device__ __forceinline__ float sigm(float x){ return 1.0f/(1.0f + __expf(-x)); }
__device__ __forceinline__ float tanh_f(float x){ return 1.0f - 2.0f/(__expf(2.0f*x)+1.0f); }
__device__ __forceinline__ float dot4(float4 a, float4 b){ return a.x*b.x + a.y*b.y + a.z*b.z + a.w*b.w; }

typedef _Float16 h2v __attribute__((ext_vector_type(2)));
__device__ __forceinline__ float fdot2(uint32_t w, uint32_t h, float acc){
  union{uint32_t u; h2v v;} a, b; a.u = w; b.u = h;
  return __builtin_amdgcn_fdot2(a.v, b.v, acc, false);
}
__device__ __forceinline__ uint32_t packh2(float x, float y){
  return (uint32_t)__half_as_ushort(__float2half(x)) |
         ((uint32_t)__half_as_ushort(__float2half(y)) << 16);
}

// Wave-synchronous LDS phase boundary: drain LDS pipe (in-order per wave) so
// one lane's ds_write is visible to every lane's subsequent ds_read. The
// "memory" clobber stops the compiler from moving LDS ops across it.
#define WSYNC() asm volatile("s_waitcnt lgkmcnt(0)" ::: "memory")

// ws layout (32-bit words):
//   [0,4096)         Wih0h fp16-pairs: word idx (m*512+g)*4+q, m<2, q<4 -> w[g][8m+2q..+1]
//   [4096,36864)     Whh0h: m<16
//   [36864,69632)    Wih1h: m<16
//   [69632,102400)   Whh1h: m<16
//   [102400,102912)  b0 = bih0+bhh0 (f32)
//   [102912,103424)  b1 = bih1+bhh1 (f32)
//   [103424,300032)  alpha (512,128,3) f32

__global__ void prep_kernel(const float* __restrict__ Wih0, const float* __restrict__ Whh0,
                            const float* __restrict__ bih0, const float* __restrict__ bhh0,
                            const float* __restrict__ Wih1, const float* __restrict__ Whh1,
                            const float* __restrict__ bih1, const float* __restrict__ bhh1,
                            uint32_t* __restrict__ ws) {
  int idx = blockIdx.x*256 + threadIdx.x;
  if (idx < 4096) {
    int q = idx & 3, g = (idx >> 2) & 511, m = idx >> 11;
    int k0 = 8*m + 2*q;
    ws[idx] = packh2(Wih0[g*DA + k0], Wih0[g*DA + k0 + 1]);
  } else if (idx < 36864) {
    int f = idx - 4096;
    int q = f & 3, g = (f >> 2) & 511, m = f >> 11;
    int k0 = 8*m + 2*q;
    ws[idx] = packh2(Whh0[g*HH + k0], Whh0[g*HH + k0 + 1]);
  } else if (idx < 69632) {
    int f = idx - 36864;
    int q = f & 3, g = (f >> 2) & 511, m = f >> 11;
    int k0 = 8*m + 2*q;
    ws[idx] = packh2(Wih1[g*HH + k0], Wih1[g*HH + k0 + 1]);
  } else if (idx < 102400) {
    int f = idx - 69632;
    int q = f & 3, g = (f >> 2) & 511, m = f >> 11;
    int k0 = 8*m + 2*q;
    ws[idx] = packh2(Whh1[g*HH + k0], Whh1[g*HH + k0 + 1]);
  } else if (idx < 102912) {
    int j = idx - 102400;
    ((float*)ws)[idx] = bih0[j] + bhh0[j];
  } else if (idx < 103424) {
    int j = idx - 102912;
    ((float*)ws)[idx] = bih1[j] + bhh1[j];
  }
}

// Persistent 2-layer LSTM v10 = r8 (register-resident weights) + r6 (dual-row).
// (unchanged this round)
__global__ __launch_bounds__(512, 2) void lstm_kernel(
    const float* __restrict__ a, const float* __restrict__ a0,
    const uint32_t* __restrict__ wsw, const float* __restrict__ Wlin,
    const float* __restrict__ blin, float* __restrict__ alpha_out) {
  const uint4* Wih0p = (const uint4*)(wsw);
  const uint4* Whh0p = (const uint4*)(wsw + 4096);
  const uint4* Wih1p = (const uint4*)(wsw + 36864);
  const uint4* Whh1p = (const uint4*)(wsw + 69632);
  const float* b0v = (const float*)(wsw + 102400);
  const float* b1v = (const float*)(wsw + 102912);

  __shared__ __align__(16) uint32_t sxh[2][T_LEN][8];
  __shared__ __align__(16) uint32_t sh0h[2][64];
  __shared__ __align__(16) uint32_t sh1h[2][64];
  __shared__ float gates[2][4*HH];

  int tid = threadIdx.x;
  int lane = tid & 63;
  int wv = tid >> 6;
  int bb = blockIdx.x * 2;

  uint4 wi0[2], wh0[16], wi1[16], wh1[16];
  #pragma unroll
  for (int m = 0; m < 2; ++m)  wi0[m] = Wih0p[m*512 + tid];
  #pragma unroll
  for (int m = 0; m < 16; ++m) wh0[m] = Whh0p[m*512 + tid];
  #pragma unroll
  for (int m = 0; m < 16; ++m) wi1[m] = Wih1p[m*512 + tid];
  #pragma unroll
  for (int m = 0; m < 16; ++m) wh1[m] = Whh1p[m*512 + tid];
  float bi0 = b0v[tid], bi1 = b1v[tid];

  for (int i = tid; i < 2*T_LEN*8; i += 512) {
    int r = i / (T_LEN*8), rem = i % (T_LEN*8), t = rem >> 3, p = rem & 7;
    float x0, x1;
    if (t == 0) { x0 = a0[2*p]; x1 = a0[2*p+1]; }
    else {
      const float* src = a + ((size_t)(bb + r)*T_LEN + (t-1))*DA;
      x0 = src[2*p]; x1 = src[2*p+1];
    }
    sxh[r][t][p] = packh2(x0, x1);
  }
  float wl00 = Wlin[0*HH + 2*lane], wl01 = Wlin[0*HH + 2*lane+1];
  float wl10 = Wlin[1*HH + 2*lane], wl11 = Wlin[1*HH + 2*lane+1];
  float wl20 = Wlin[2*HH + 2*lane], wl21 = Wlin[2*HH + 2*lane+1];
  float bl0 = blin[0], bl1 = blin[1], bl2 = blin[2];
  float c00 = 0.f, c01 = 0.f, c10 = 0.f, c11 = 0.f;
  if (tid < 128) { sh0h[wv][lane] = 0u; sh1h[wv][lane] = 0u; }
  __syncthreads();

  #pragma unroll 1
  for (int t = 0; t < T_LEN; ++t) {
    {
      float g0a = bi0, g0b = 0.f, g1a = bi0, g1b = 0.f;
      uint4 xA0 = *(const uint4*)&sxh[0][t][0];
      uint4 xA1 = *(const uint4*)&sxh[0][t][4];
      uint4 xB0 = *(const uint4*)&sxh[1][t][0];
      uint4 xB1 = *(const uint4*)&sxh[1][t][4];
      g0a = fdot2(wi0[0].x, xA0.x, g0a); g0b = fdot2(wi0[0].y, xA0.y, g0b);
      g0a = fdot2(wi0[0].z, xA0.z, g0a); g0b = fdot2(wi0[0].w, xA0.w, g0b);
      g0a = fdot2(wi0[1].x, xA1.x, g0a); g0b = fdot2(wi0[1].y, xA1.y, g0b);
      g0a = fdot2(wi0[1].z, xA1.z, g0a); g0b = fdot2(wi0[1].w, xA1.w, g0b);
      g1a = fdot2(wi0[0].x, xB0.x, g1a); g1b = fdot2(wi0[0].y, xB0.y, g1b);
      g1a = fdot2(wi0[0].z, xB0.z, g1a); g1b = fdot2(wi0[0].w, xB0.w, g1b);
      g1a = fdot2(wi0[1].x, xB1.x, g1a); g1b = fdot2(wi0[1].y, xB1.y, g1b);
      g1a = fdot2(wi0[1].z, xB1.z, g1a); g1b = fdot2(wi0[1].w, xB1.w, g1b);
      #pragma unroll
      for (int m = 0; m < 16; ++m) {
        uint4 w = wh0[m];
        uint4 hA = *(const uint4*)&sh0h[0][4*m];
        uint4 hB = *(const uint4*)&sh0h[1][4*m];
        g0a = fdot2(w.x, hA.x, g0a); g0b = fdot2(w.y, hA.y, g0b);
        g0a = fdot2(w.z, hA.z, g0a); g0b = fdot2(w.w, hA.w, g0b);
        g1a = fdot2(w.x, hB.x, g1a); g1b = fdot2(w.y, hB.y, g1b);
        g1a = fdot2(w.z, hB.z, g1a); g1b = fdot2(w.w, hB.w, g1b);
      }
      gates[0][tid] = g0a + g0b;
      gates[1][tid] = g1a + g1b;
    }
    __syncthreads();                                   // B1
    if (tid < 128) {
      int j0 = 2*lane, j1 = j0 + 1;
      float i0 = gates[wv][j0],      f0 = gates[wv][j0+HH],
            q0 = gates[wv][j0+2*HH], o0 = gates[wv][j0+3*HH];
      c00 = sigm(f0)*c00 + sigm(i0)*tanh_f(q0);
      float hv0 = sigm(o0)*tanh_f(c00);
      float i1 = gates[wv][j1],      f1 = gates[wv][j1+HH],
            q1 = gates[wv][j1+2*HH], o1 = gates[wv][j1+3*HH];
      c01 = sigm(f1)*c01 + sigm(i1)*tanh_f(q1);
      float hv1 = sigm(o1)*tanh_f(c01);
      sh0h[wv][lane] = packh2(hv0, hv1);
    }
    __syncthreads();                                   // B2
    {
      float g0a = bi1, g0b = 0.f, g1a = bi1, g1b = 0.f;
      #pragma unroll
      for (int m = 0; m < 16; ++m) {
        uint4 w = wi1[m];
        uint4 hA = *(const uint4*)&sh0h[0][4*m];
        uint4 hB = *(const uint4*)&sh0h[1][4*m];
        g0a = fdot2(w.x, hA.x, g0a); g0b = fdot2(w.y, hA.y, g0b);
        g0a = fdot2(w.z, hA.z, g0a); g0b = fdot2(w.w, hA.w, g0b);
        g1a = fdot2(w.x, hB.x, g1a); g1b = fdot2(w.y, hB.y, g1b);
        g1a = fdot2(w.z, hB.z, g1a); g1b = fdot2(w.w, hB.w, g1b);
      }
      #pragma unroll
      for (int m = 0; m < 16; ++m) {
        uint4 w = wh1[m];
        uint4 hA = *(const uint4*)&sh1h[0][4*m];
        uint4 hB = *(const uint4*)&sh1h[1][4*m];
        g0a = fdot2(w.x, hA.x, g0a); g0b = fdot2(w.y, hA.y, g0b);
        g0a = fdot2(w.z, hA.z, g0a); g0b = fdot2(w.w, hA.w, g0b);
        g1a = fdot2(w.x, hB.x, g1a); g1b = fdot2(w.y, hB.y, g1b);
        g1a = fdot2(w.z, hB.z, g1a); g1b = fdot2(w.w, hB.w, g1b);
      }
      gates[0][tid] = g0a + g0b;
      gates[1][tid] = g1a + g1b;
    }
    __syncthreads();                                   // B3
    float hv0 = 0.f, hv1 = 0.f;
    if (tid < 128) {
      int j0 = 2*lane, j1 = j0 + 1;
      float i0 = gates[wv][j0],      f0 = gates[wv][j0+HH],
            q0 = gates[wv][j0+2*HH], o0 = gates[wv][j0+3*HH];
      c10 = sigm(f0)*c10 + sigm(i0)*tanh_f(q0);
      hv0 = sigm(o0)*tanh_f(c10);
      float i1 = gates[wv][j1],      f1 = gates[wv][j1+HH],
            q1 = gates[wv][j1+2*HH], o1 = gates[wv][j1+3*HH];
      c11 = sigm(f1)*c11 + sigm(i1)*tanh_f(q1);
      hv1 = sigm(o1)*tanh_f(c11);
      sh1h[wv][lane] = packh2(hv0, hv1);
    }
    __syncthreads();                                   // B4
    if (tid < 128) {
      float p0 = hv0*wl00 + hv1*wl01;
      float p1 = hv0*wl10 + hv1*wl11;
      float p2 = hv0*wl20 + hv1*wl21;
      #pragma unroll
      for (int off = 32; off > 0; off >>= 1) {
        p0 += __shfl_down(p0, off); p1 += __shfl_down(p1, off); p2 += __shfl_down(p2, off);
      }
      if (lane == 0) {
        float l0 = p0 + bl0, l1 = p1 + bl1, l2 = p2 + bl2;
        float mx = fmaxf(l0, fmaxf(l1, l2));
        float e0=__expf(l0-mx), e1=__expf(l1-mx), e2=__expf(l2-mx);
        float inv = 1.0f/(e0+e1+e2);
        float* dst = alpha_out + (((size_t)(bb+wv))*T_LEN + t)*3;
        dst[0]=e0*inv; dst[1]=e1*inv; dst[2]=e2*inv;
      }
    }
  }
}

// Kalman scan v5: single-wave-per-batch (512 blocks x 64 threads), zero
// barriers (wave-synchronous, WSYNC = lgkmcnt drain at phase boundaries),
// 4x4 register output tiles everywhere (8x8 lane grid) so each 32-wide
// matmul costs 64 ds_read_b128/wave instead of 160, and row.row dot
// formulations (Sg=T2*Am^T, N=Sg*Cm^T, Sp2=Sg-Kg*Nn^T, Kg=Nn*Sinv using
// Sinv symmetry) eliminate AmT/Sp2T entirely. LDS wave-instr count per
// batch-step drops ~650 -> ~400; the kernel was LDS-pipe-bound (measured
// 16K cyc/step == 2 blocks x 650 b128 x 12cyc), so predict ~2x.
__global__ __launch_bounds__(64, 1) void kalman_kernel(
    const float* __restrict__ a, const float* __restrict__ A,
    const float* __restrict__ C, const float* __restrict__ alpha,
    float* __restrict__ out) {
  __shared__ __align__(16) float Sg[DZ][36];
  __shared__ __align__(16) float Am[DZ][36];
  __shared__ __align__(16) float Cm[DA][36];
  __shared__ __align__(16) float Nn[DZ][20];
  __shared__ __align__(16) float NnT[DA][36];
  __shared__ __align__(16) float Aug[DA][36];
  __shared__ __align__(16) float Kg[DZ][20];
  __shared__ __align__(16) float Sp2[DZ][36];
  __shared__ __align__(16) float T2m[DZ][36];
  __shared__ __align__(16) float sa[T_LEN][DA];
  __shared__ float salpha[T_LEN*3];
  __shared__ __align__(16) float muv[DZ];
  __shared__ __align__(16) float mun[DZ];
  __shared__ __align__(16) float rv[DA];

  const int l  = threadIdx.x;        // 0..63
  const int bi = l >> 3;             // 0..7
  const int bj = l & 7;              // 0..7
  const int b  = blockIdx.x;

  // ---- staging ----
  {
    const float4* asrc = (const float4*)(a + (size_t)b*T_LEN*DA);
    float4* adst = (float4*)&sa[0][0];
    #pragma unroll
    for (int e = 0; e < 8; ++e) adst[e*64 + l] = asrc[e*64 + l];
    const float* alsrc = alpha + (size_t)b*T_LEN*3;
    #pragma unroll
    for (int e = 0; e < 6; ++e) salpha[e*64 + l] = alsrc[e*64 + l];
    for (int i = l; i < DZ*36; i += 64) (&Sg[0][0])[i] = 0.0f;
    if (l < DZ) muv[l] = 0.0f;
  }
  WSYNC();
  if (l < DZ) Sg[l][l] = 1.0f;
  WSYNC();

  const float4* A4 = (const float4*)A;   // (K,T,32 rows,8 float4)
  const float4* C4 = (const float4*)C;   // (K,T,16 rows,8 float4)

  // prefetch for t=0: A at ta=1, C at t=0. Lane tile: A rows 4bi..+3, cols 4bj..+3;
  // C rows 2bi..+1, cols 4bj..+3.
  float4 pA[3][4], pC[3][2];
  #pragma unroll
  for (int k = 0; k < 3; ++k) {
    #pragma unroll
    for (int r = 0; r < 4; ++r) pA[k][r] = A4[((k*T_LEN + 1)*DZ + 4*bi + r)*8 + bj];
    #pragma unroll
    for (int r = 0; r < 2; ++r) pC[k][r] = C4[((k*T_LEN + 0)*DA + 2*bi + r)*8 + bj];
  }

  #pragma unroll 1
  for (int t = 0; t < T_LEN; ++t) {
    const int ta = (t < T_LEN-1) ? t+1 : t;
    const float b10 = salpha[ta*3+0], b11 = salpha[ta*3+1], b12 = salpha[ta*3+2];
    const float b00 = salpha[t*3+0],  b01 = salpha[t*3+1],  b02 = salpha[t*3+2];

    // ---- ph0: mix Am (alpha[ta]) and Cm (alpha[t]); prefetch next ----
    #pragma unroll
    for (int r = 0; r < 4; ++r) {
      float4 v;
      v.x = b10*pA[0][r].x + b11*pA[1][r].x + b12*pA[2][r].x;
      v.y = b10*pA[0][r].y + b11*pA[1][r].y + b12*pA[2][r].y;
      v.z = b10*pA[0][r].z + b11*pA[1][r].z + b12*pA[2][r].z;
      v.w = b10*pA[0][r].w + b11*pA[1][r].w + b12*pA[2][r].w;
      *(float4*)&Am[4*bi+r][4*bj] = v;
    }
    #pragma unroll
    for (int r = 0; r < 2; ++r) {
      float4 c;
      c.x = b00*pC[0][r].x + b01*pC[1][r].x + b02*pC[2][r].x;
      c.y = b00*pC[0][r].y + b01*pC[1][r].y + b02*pC[2][r].y;
      c.z = b00*pC[0][r].z + b01*pC[1][r].z + b02*pC[2][r].z;
      c.w = b00*pC[0][r].w + b01*pC[1][r].w + b02*pC[2][r].w;
      *(float4*)&Cm[2*bi+r][4*bj] = c;
    }
    {
      const int tn  = (t+1 < T_LEN) ? t+1 : T_LEN-1;
      const int tan = (tn < T_LEN-1) ? tn+1 : tn;
      #pragma unroll
      for (int k = 0; k < 3; ++k) {
        #pragma unroll
        for (int r = 0; r < 4; ++r) pA[k][r] = A4[((k*T_LEN + tan)*DZ + 4*bi + r)*8 + bj];
        #pragma unroll
        for (int r = 0; r < 2; ++r) pC[k][r] = C4[((k*T_LEN + tn)*DA + 2*bi + r)*8 + bj];
      }
    }
    WSYNC();

    // ---- ph1: N = Sg*Cm^T (tile 4 rows x 2 cols), r = a_t - Cm*mu ----
    {
      float accA[4] = {0.f,0.f,0.f,0.f}, accB[4] = {0.f,0.f,0.f,0.f};
      #pragma unroll
      for (int k4 = 0; k4 < 8; ++k4) {
        float4 cA = *(const float4*)&Cm[2*bj][4*k4];
        float4 cB = *(const float4*)&Cm[2*bj+1][4*k4];
        #pragma unroll
        for (int r = 0; r < 4; ++r) {
          float4 s = *(const float4*)&Sg[4*bi+r][4*k4];
          accA[r] += dot4(s, cA); accB[r] += dot4(s, cB);
        }
      }
      #pragma unroll
      for (int r = 0; r < 4; ++r)
        *(float2*)&Nn[4*bi+r][2*bj] = make_float2(accA[r], accB[r]);
      *(float4*)&NnT[2*bj][4*bi]   = make_float4(accA[0], accA[1], accA[2], accA[3]);
      *(float4*)&NnT[2*bj+1][4*bi] = make_float4(accB[0], accB[1], accB[2], accB[3]);
      if (l < DA) {
        float acc = sa[t][l];
        #pragma unroll
        for (int k4 = 0; k4 < 8; ++k4)
          acc -= dot4(*(const float4*)&Cm[l][4*k4], *(const float4*)&muv[4*k4]);
        rv[l] = acc;
      }
    }
    WSYNC();

    // ---- ph2: Aug = Cm*N + R | I  (S[i][j] = dot(Cm row i, NnT row j)) ----
    {
      float a00=0.f, a01=0.f, a10=0.f, a11=0.f;
      #pragma unroll
      for (int k4 = 0; k4 < 8; ++k4) {
        float4 c0 = *(const float4*)&Cm[2*bi][4*k4];
        float4 c1 = *(const float4*)&Cm[2*bi+1][4*k4];
        float4 n0 = *(const float4*)&NnT[2*bj][4*k4];
        float4 n1 = *(const float4*)&NnT[2*bj+1][4*k4];
        a00 += dot4(c0,n0); a01 += dot4(c0,n1);
        a10 += dot4(c1,n0); a11 += dot4(c1,n1);
      }
      const int i0 = 2*bi, j0 = 2*bj;
      a00 += (i0   == j0  ) ? 0.01f : 0.f;
      a01 += (i0   == j0+1) ? 0.01f : 0.f;
      a10 += (i0+1 == j0  ) ? 0.01f : 0.f;
      a11 += (i0+1 == j0+1) ? 0.01f : 0.f;
      *(float2*)&Aug[i0][j0]   = make_float2(a00, a01);
      *(float2*)&Aug[i0+1][j0] = make_float2(a10, a11);
      *(float2*)&Aug[i0][16+j0]   = make_float2((i0==j0)?1.f:0.f, (i0==j0+1)?1.f:0.f);
      *(float2*)&Aug[i0+1][16+j0] = make_float2((i0+1==j0)?1.f:0.f, (i0+1==j0+1)?1.f:0.f);
    }
    WSYNC();

    // ---- ph3: wave-synchronous Gauss-Jordan (unchanged, whole wave) ----
    {
      int r = l >> 2, cb = l & 3;
      float v[8];
      #pragma unroll
      for (int j = 0; j < 8; ++j) v[j] = Aug[r][cb*8 + j];
      #pragma unroll
      for (int p = 0; p < DA; ++p) {
        float App = __shfl(v[p & 7], (p << 2) | (p >> 3), 64);
        float f   = __shfl(v[p & 7], (l & 60) | (p >> 3), 64);
        float prow[8];
        #pragma unroll
        for (int j = 0; j < 8; ++j) prow[j] = __shfl(v[j], (p << 2) | cb, 64);
        float pinv = 1.0f / App;
        if (r == p) {
          #pragma unroll
          for (int j = 0; j < 8; ++j) v[j] *= pinv;
        } else {
          float fp = f * pinv;
          #pragma unroll
          for (int j = 0; j < 8; ++j) v[j] -= fp * prow[j];
        }
      }
      if (cb >= 2) {
        #pragma unroll
        for (int j = 0; j < 8; ++j) Aug[r][cb*8 + j] = v[j];
      }
    }
    WSYNC();

    // ---- ph4: Kg = Nn*Sinv (Sinv symmetric -> row.row; tile 4x2) ----
    {
      float kA[4] = {0.f,0.f,0.f,0.f}, kB[4] = {0.f,0.f,0.f,0.f};
      #pragma unroll
      for (int k4 = 0; k4 < 4; ++k4) {
        float4 siA = *(const float4*)&Aug[2*bj][16+4*k4];
        float4 siB = *(const float4*)&Aug[2*bj+1][16+4*k4];
        #pragma unroll
        for (int r = 0; r < 4; ++r) {
          float4 n = *(const float4*)&Nn[4*bi+r][4*k4];
          kA[r] += dot4(n, siA); kB[r] += dot4(n, siB);
        }
      }
      #pragma unroll
      for (int r = 0; r < 4; ++r)
        *(float2*)&Kg[4*bi+r][2*bj] = make_float2(kA[r], kB[r]);
    }
    WSYNC();

    // ---- ph5: mu update + out; Sp2 = Sg - Kg*Nn^T (tile 4x4, row.row) ----
    if (l < DZ) {
      float m = muv[l];
      #pragma unroll
      for (int k4 = 0; k4 < 4; ++k4)
        m += dot4(*(const float4*)&Kg[l][4*k4], *(const float4*)&rv[4*k4]);
      mun[l] = m;
      out[((size_t)b*T_LEN + t)*DZ + l] = m;
    }
    {
      float4 acc[4];
      #pragma unroll
      for (int r = 0; r < 4; ++r) acc[r] = *(const float4*)&Sg[4*bi+r][4*bj];
      #pragma unroll
      for (int k4 = 0; k4 < 4; ++k4) {
        float4 n0 = *(const float4*)&Nn[4*bj+0][4*k4];
        float4 n1 = *(const float4*)&Nn[4*bj+1][4*k4];
        float4 n2 = *(const float4*)&Nn[4*bj+2][4*k4];
        float4 n3 = *(const float4*)&Nn[4*bj+3][4*k4];
        #pragma unroll
        for (int r = 0; r < 4; ++r) {
          float4 kg = *(const float4*)&Kg[4*bi+r][4*k4];
          acc[r].x -= dot4(kg, n0); acc[r].y -= dot4(kg, n1);
          acc[r].z -= dot4(kg, n2); acc[r].w -= dot4(kg, n3);
        }
      }
      #pragma unroll
      for (int r = 0; r < 4; ++r) *(float4*)&Sp2[4*bi+r][4*bj] = acc[r];
    }
    WSYNC();

    // ---- ph6: T2 = Am*Sp2 (k-major: Sp2 read by rows, no transpose) ----
    {
      float4 acc[4] = {{0,0,0,0},{0,0,0,0},{0,0,0,0},{0,0,0,0}};
      #pragma unroll
      for (int k4 = 0; k4 < 8; ++k4) {
        float4 sp0 = *(const float4*)&Sp2[4*k4+0][4*bj];
        float4 sp1 = *(const float4*)&Sp2[4*k4+1][4*bj];
        float4 sp2v= *(const float4*)&Sp2[4*k4+2][4*bj];
        float4 sp3 = *(const float4*)&Sp2[4*k4+3][4*bj];
        #pragma unroll
        for (int r = 0; r < 4; ++r) {
          float4 am = *(const float4*)&Am[4*bi+r][4*k4];
          acc[r].x += am.x*sp0.x + am.y*sp1.x + am.z*sp2v.x + am.w*sp3.x;
          acc[r].y += am.x*sp0.y + am.y*sp1.y + am.z*sp2v.y + am.w*sp3.y;
          acc[r].z += am.x*sp0.z + am.y*sp1.z + am.z*sp2v.z + am.w*sp3.z;
          acc[r].w += am.x*sp0.w + am.y*sp1.w + am.z*sp2v.w + am.w*sp3.w;
        }
      }
      #pragma unroll
      for (int r = 0; r < 4; ++r) *(float4*)&T2m[4*bi+r][4*bj] = acc[r];
    }
    WSYNC();

    // ---- ph7: Sg = T2*Am^T + Q (row.row); mu_next = Am*mun ----
    {
      float4 acc[4] = {{0,0,0,0},{0,0,0,0},{0,0,0,0},{0,0,0,0}};
      #pragma unroll
      for (int k4 = 0; k4 < 8; ++k4) {
        float4 am0 = *(const float4*)&Am[4*bj+0][4*k4];
        float4 am1 = *(const float4*)&Am[4*bj+1][4*k4];
        float4 am2 = *(const float4*)&Am[4*bj+2][4*k4];
        float4 am3 = *(const float4*)&Am[4*bj+3][4*k4];
        #pragma unroll
        for (int r = 0; r < 4; ++r) {
          float4 t2 = *(const float4*)&T2m[4*bi+r][4*k4];
          acc[r].x += dot4(t2, am0); acc[r].y += dot4(t2, am1);
          acc[r].z += dot4(t2, am2); acc[r].w += dot4(t2, am3);
        }
      }
      if (bi == bj) {
        acc[0].x += 0.01f; acc[1].y += 0.01f; acc[2].z += 0.01f; acc[3].w += 0.01f;
      }
      #pragma unroll
      for (int r = 0; r < 4; ++r) *(float4*)&Sg[4*bi+r][4*bj] = acc[r];
      if (l < DZ) {
        float m = 0.0f;
        #pragma unroll
        for (int k4 = 0; k4 < 8; ++k4)
          m += dot4(*(const float4*)&Am[l][4*k4], *(const float4*)&mun[4*k4]);
        muv[l] = m;
      }
    }
    WSYNC();
  }
}

extern "C" void kernel_launch(void* const* d_in, const int* in_sizes, int n_in,
                              void* d_out, int out_size, void* d_ws, size_t ws_size,
                              hipStream_t stream) {
  const float* a    = (const float*)d_in[0];
  const float* A    = (const float*)d_in[1];
  const float* C    = (const float*)d_in[2];
  const float* a0   = (const float*)d_in[3];
  const float* Wih0 = (const float*)d_in[4];
  const float* Whh0 = (const float*)d_in[5];
  const float* bih0 = (const float*)d_in[6];
  const float* bhh0 = (const float*)d_in[7];
  const float* Wih1 = (const float*)d_in[8];
  const float* Whh1 = (const float*)d_in[9];
  const float* bih1 = (const float*)d_in[10];
  const float* bhh1 = (const float*)d_in[11];
  const float* Wlin = (const float*)d_in[12];
  const float* blin = (const float*)d_in[13];
  uint32_t* ws = (uint32_t*)d_ws;
  float* alpha = (float*)(ws + 103424);
  float* out = (float*)d_out;

  prep_kernel<<<404, 256, 0, stream>>>(Wih0, Whh0, bih0, bhh0, Wih1, Whh1, bih1, bhh1, ws);
  lstm_kernel<<<256, 512, 0, stream>>>(a, a0, ws, Wlin, blin, alpha);
  kalman_kernel<<<512, 64, 0, stream>>>(a, A, C, alpha, out);
}

// Round 2
// 1392.235 us; speedup vs baseline: 1.1241x; 1.1241x over previous
//
#include <hip/hip_runtime.h>
#include <hip/hip_fp16.h>
#include <cstdint>

#define T_LEN 128
#define DA    16
#define DZ    32
#define HH    128

__device__ __forceinline__ float sigm(float x){ return 1.0f/(1.0f + __expf(-x)); }
__device__ __forceinline__ float tanh_f(float x){ return 1.0f - 2.0f/(__expf(2.0f*x)+1.0f); }
__device__ __forceinline__ float dot4(float4 a, float4 b){ return a.x*b.x + a.y*b.y + a.z*b.z + a.w*b.w; }

typedef _Float16 h2v __attribute__((ext_vector_type(2)));
__device__ __forceinline__ float fdot2(uint32_t w, uint32_t h, float acc){
  union{uint32_t u; h2v v;} a, b; a.u = w; b.u = h;
  return __builtin_amdgcn_fdot2(a.v, b.v, acc, false);
}
__device__ __forceinline__ uint32_t packh2(float x, float y){
  return (uint32_t)__half_as_ushort(__float2half(x)) |
         ((uint32_t)__half_as_ushort(__float2half(y)) << 16);
}

// LDS-only barrier: drain LDS pipe (write visibility), then raw s_barrier.
// Unlike __syncthreads() this does NOT emit s_waitcnt vmcnt(0), so global
// prefetch loads (and the out store) stay in flight across phase boundaries.
#define BAR() do { asm volatile("s_waitcnt lgkmcnt(0)" ::: "memory"); \
                   __builtin_amdgcn_s_barrier(); } while (0)

// ws layout (32-bit words):
//   [0,4096)         Wih0h fp16-pairs: word idx (m*512+g)*4+q, m<2, q<4 -> w[g][8m+2q..+1]
//   [4096,36864)     Whh0h: m<16
//   [36864,69632)    Wih1h: m<16
//   [69632,102400)   Whh1h: m<16
//   [102400,102912)  b0 = bih0+bhh0 (f32)
//   [102912,103424)  b1 = bih1+bhh1 (f32)
//   [103424,300032)  alpha (512,128,3) f32

__global__ void prep_kernel(const float* __restrict__ Wih0, const float* __restrict__ Whh0,
                            const float* __restrict__ bih0, const float* __restrict__ bhh0,
                            const float* __restrict__ Wih1, const float* __restrict__ Whh1,
                            const float* __restrict__ bih1, const float* __restrict__ bhh1,
                            uint32_t* __restrict__ ws) {
  int idx = blockIdx.x*256 + threadIdx.x;
  if (idx < 4096) {
    int q = idx & 3, g = (idx >> 2) & 511, m = idx >> 11;
    int k0 = 8*m + 2*q;
    ws[idx] = packh2(Wih0[g*DA + k0], Wih0[g*DA + k0 + 1]);
  } else if (idx < 36864) {
    int f = idx - 4096;
    int q = f & 3, g = (f >> 2) & 511, m = f >> 11;
    int k0 = 8*m + 2*q;
    ws[idx] = packh2(Whh0[g*HH + k0], Whh0[g*HH + k0 + 1]);
  } else if (idx < 69632) {
    int f = idx - 36864;
    int q = f & 3, g = (f >> 2) & 511, m = f >> 11;
    int k0 = 8*m + 2*q;
    ws[idx] = packh2(Wih1[g*HH + k0], Wih1[g*HH + k0 + 1]);
  } else if (idx < 102400) {
    int f = idx - 69632;
    int q = f & 3, g = (f >> 2) & 511, m = f >> 11;
    int k0 = 8*m + 2*q;
    ws[idx] = packh2(Whh1[g*HH + k0], Whh1[g*HH + k0 + 1]);
  } else if (idx < 102912) {
    int j = idx - 102400;
    ((float*)ws)[idx] = bih0[j] + bhh0[j];
  } else if (idx < 103424) {
    int j = idx - 102912;
    ((float*)ws)[idx] = bih1[j] + bhh1[j];
  }
}

// Persistent 2-layer LSTM (unchanged: register-resident weights + dual-row).
__global__ __launch_bounds__(512, 2) void lstm_kernel(
    const float* __restrict__ a, const float* __restrict__ a0,
    const uint32_t* __restrict__ wsw, const float* __restrict__ Wlin,
    const float* __restrict__ blin, float* __restrict__ alpha_out) {
  const uint4* Wih0p = (const uint4*)(wsw);
  const uint4* Whh0p = (const uint4*)(wsw + 4096);
  const uint4* Wih1p = (const uint4*)(wsw + 36864);
  const uint4* Whh1p = (const uint4*)(wsw + 69632);
  const float* b0v = (const float*)(wsw + 102400);
  const float* b1v = (const float*)(wsw + 102912);

  __shared__ __align__(16) uint32_t sxh[2][T_LEN][8];
  __shared__ __align__(16) uint32_t sh0h[2][64];
  __shared__ __align__(16) uint32_t sh1h[2][64];
  __shared__ float gates[2][4*HH];

  int tid = threadIdx.x;
  int lane = tid & 63;
  int wv = tid >> 6;
  int bb = blockIdx.x * 2;

  uint4 wi0[2], wh0[16], wi1[16], wh1[16];
  #pragma unroll
  for (int m = 0; m < 2; ++m)  wi0[m] = Wih0p[m*512 + tid];
  #pragma unroll
  for (int m = 0; m < 16; ++m) wh0[m] = Whh0p[m*512 + tid];
  #pragma unroll
  for (int m = 0; m < 16; ++m) wi1[m] = Wih1p[m*512 + tid];
  #pragma unroll
  for (int m = 0; m < 16; ++m) wh1[m] = Whh1p[m*512 + tid];
  float bi0 = b0v[tid], bi1 = b1v[tid];

  for (int i = tid; i < 2*T_LEN*8; i += 512) {
    int r = i / (T_LEN*8), rem = i % (T_LEN*8), t = rem >> 3, p = rem & 7;
    float x0, x1;
    if (t == 0) { x0 = a0[2*p]; x1 = a0[2*p+1]; }
    else {
      const float* src = a + ((size_t)(bb + r)*T_LEN + (t-1))*DA;
      x0 = src[2*p]; x1 = src[2*p+1];
    }
    sxh[r][t][p] = packh2(x0, x1);
  }
  float wl00 = Wlin[0*HH + 2*lane], wl01 = Wlin[0*HH + 2*lane+1];
  float wl10 = Wlin[1*HH + 2*lane], wl11 = Wlin[1*HH + 2*lane+1];
  float wl20 = Wlin[2*HH + 2*lane], wl21 = Wlin[2*HH + 2*lane+1];
  float bl0 = blin[0], bl1 = blin[1], bl2 = blin[2];
  float c00 = 0.f, c01 = 0.f, c10 = 0.f, c11 = 0.f;
  if (tid < 128) { sh0h[wv][lane] = 0u; sh1h[wv][lane] = 0u; }
  __syncthreads();

  #pragma unroll 1
  for (int t = 0; t < T_LEN; ++t) {
    {
      float g0a = bi0, g0b = 0.f, g1a = bi0, g1b = 0.f;
      uint4 xA0 = *(const uint4*)&sxh[0][t][0];
      uint4 xA1 = *(const uint4*)&sxh[0][t][4];
      uint4 xB0 = *(const uint4*)&sxh[1][t][0];
      uint4 xB1 = *(const uint4*)&sxh[1][t][4];
      g0a = fdot2(wi0[0].x, xA0.x, g0a); g0b = fdot2(wi0[0].y, xA0.y, g0b);
      g0a = fdot2(wi0[0].z, xA0.z, g0a); g0b = fdot2(wi0[0].w, xA0.w, g0b);
      g0a = fdot2(wi0[1].x, xA1.x, g0a); g0b = fdot2(wi0[1].y, xA1.y, g0b);
      g0a = fdot2(wi0[1].z, xA1.z, g0a); g0b = fdot2(wi0[1].w, xA1.w, g0b);
      g1a = fdot2(wi0[0].x, xB0.x, g1a); g1b = fdot2(wi0[0].y, xB0.y, g1b);
      g1a = fdot2(wi0[0].z, xB0.z, g1a); g1b = fdot2(wi0[0].w, xB0.w, g1b);
      g1a = fdot2(wi0[1].x, xB1.x, g1a); g1b = fdot2(wi0[1].y, xB1.y, g1b);
      g1a = fdot2(wi0[1].z, xB1.z, g1a); g1b = fdot2(wi0[1].w, xB1.w, g1b);
      #pragma unroll
      for (int m = 0; m < 16; ++m) {
        uint4 w = wh0[m];
        uint4 hA = *(const uint4*)&sh0h[0][4*m];
        uint4 hB = *(const uint4*)&sh0h[1][4*m];
        g0a = fdot2(w.x, hA.x, g0a); g0b = fdot2(w.y, hA.y, g0b);
        g0a = fdot2(w.z, hA.z, g0a); g0b = fdot2(w.w, hA.w, g0b);
        g1a = fdot2(w.x, hB.x, g1a); g1b = fdot2(w.y, hB.y, g1b);
        g1a = fdot2(w.z, hB.z, g1a); g1b = fdot2(w.w, hB.w, g1b);
      }
      gates[0][tid] = g0a + g0b;
      gates[1][tid] = g1a + g1b;
    }
    __syncthreads();                                   // B1
    if (tid < 128) {
      int j0 = 2*lane, j1 = j0 + 1;
      float i0 = gates[wv][j0],      f0 = gates[wv][j0+HH],
            q0 = gates[wv][j0+2*HH], o0 = gates[wv][j0+3*HH];
      c00 = sigm(f0)*c00 + sigm(i0)*tanh_f(q0);
      float hv0 = sigm(o0)*tanh_f(c00);
      float i1 = gates[wv][j1],      f1 = gates[wv][j1+HH],
            q1 = gates[wv][j1+2*HH], o1 = gates[wv][j1+3*HH];
      c01 = sigm(f1)*c01 + sigm(i1)*tanh_f(q1);
      float hv1 = sigm(o1)*tanh_f(c01);
      sh0h[wv][lane] = packh2(hv0, hv1);
    }
    __syncthreads();                                   // B2
    {
      float g0a = bi1, g0b = 0.f, g1a = bi1, g1b = 0.f;
      #pragma unroll
      for (int m = 0; m < 16; ++m) {
        uint4 w = wi1[m];
        uint4 hA = *(const uint4*)&sh0h[0][4*m];
        uint4 hB = *(const uint4*)&sh0h[1][4*m];
        g0a = fdot2(w.x, hA.x, g0a); g0b = fdot2(w.y, hA.y, g0b);
        g0a = fdot2(w.z, hA.z, g0a); g0b = fdot2(w.w, hA.w, g0b);
        g1a = fdot2(w.x, hB.x, g1a); g1b = fdot2(w.y, hB.y, g1b);
        g1a = fdot2(w.z, hB.z, g1a); g1b = fdot2(w.w, hB.w, g1b);
      }
      #pragma unroll
      for (int m = 0; m < 16; ++m) {
        uint4 w = wh1[m];
        uint4 hA = *(const uint4*)&sh1h[0][4*m];
        uint4 hB = *(const uint4*)&sh1h[1][4*m];
        g0a = fdot2(w.x, hA.x, g0a); g0b = fdot2(w.y, hA.y, g0b);
        g0a = fdot2(w.z, hA.z, g0a); g0b = fdot2(w.w, hA.w, g0b);
        g1a = fdot2(w.x, hB.x, g1a); g1b = fdot2(w.y, hB.y, g1b);
        g1a = fdot2(w.z, hB.z, g1a); g1b = fdot2(w.w, hB.w, g1b);
      }
      gates[0][tid] = g0a + g0b;
      gates[1][tid] = g1a + g1b;
    }
    __syncthreads();                                   // B3
    float hv0 = 0.f, hv1 = 0.f;
    if (tid < 128) {
      int j0 = 2*lane, j1 = j0 + 1;
      float i0 = gates[wv][j0],      f0 = gates[wv][j0+HH],
            q0 = gates[wv][j0+2*HH], o0 = gates[wv][j0+3*HH];
      c10 = sigm(f0)*c10 + sigm(i0)*tanh_f(q0);
      hv0 = sigm(o0)*tanh_f(c10);
      float i1 = gates[wv][j1],      f1 = gates[wv][j1+HH],
            q1 = gates[wv][j1+2*HH], o1 = gates[wv][j1+3*HH];
      c11 = sigm(f1)*c11 + sigm(i1)*tanh_f(q1);
      hv1 = sigm(o1)*tanh_f(c11);
      sh1h[wv][lane] = packh2(hv0, hv1);
    }
    __syncthreads();                                   // B4
    if (tid < 128) {
      float p0 = hv0*wl00 + hv1*wl01;
      float p1 = hv0*wl10 + hv1*wl11;
      float p2 = hv0*wl20 + hv1*wl21;
      #pragma unroll
      for (int off = 32; off > 0; off >>= 1) {
        p0 += __shfl_down(p0, off); p1 += __shfl_down(p1, off); p2 += __shfl_down(p2, off);
      }
      if (lane == 0) {
        float l0 = p0 + bl0, l1 = p1 + bl1, l2 = p2 + bl2;
        float mx = fmaxf(l0, fmaxf(l1, l2));
        float e0=__expf(l0-mx), e1=__expf(l1-mx), e2=__expf(l2-mx);
        float inv = 1.0f/(e0+e1+e2);
        float* dst = alpha_out + (((size_t)(bb+wv))*T_LEN + t)*3;
        dst[0]=e0*inv; dst[1]=e1*inv; dst[2]=e2*inv;
      }
    }
  }
}

// Kalman scan v6: back to 256 threads / 4 waves / 512 blocks (8 waves/CU for
// latency hiding — v5's single-wave variant proved the kernel is stall-bound,
// not LDS-throughput-bound). Stall attack:
//  (a) algebra restructured so both 32^3 matmuls run BEFORE the inverse:
//      AmSg = Am*Sg; G = AmSg*Am^T; M = AmSg*Cm^T (= Am*N); AmK = M*Sinv;
//      Sg' = G - AmK*M^T + Q. Post-GJ tail is only 16-wide matmuls.
//  (b) 6 barriers/step instead of 8; w = Sinv*r folded into the GJ wave.
//  (c) BAR() = lgkmcnt-only barrier: no vmcnt(0) drain, so the 18 global
//      prefetch loads stay in flight across phase boundaries.
__global__ __launch_bounds__(256, 2) void kalman_kernel(
    const float* __restrict__ a, const float* __restrict__ A,
    const float* __restrict__ C, const float* __restrict__ alpha,
    float* __restrict__ out) {
  __shared__ __align__(16) float Sg[DZ][36];
  __shared__ __align__(16) float Am[DZ][36];
  __shared__ __align__(16) float Cm[DA][36];
  __shared__ __align__(16) float AmSg[DZ][36];
  __shared__ __align__(16) float Gm[DZ][36];
  __shared__ __align__(16) float Nn[DZ][20];
  __shared__ __align__(16) float NnT[DA][36];
  __shared__ __align__(16) float Mm[DZ][20];
  __shared__ __align__(16) float Aug[DA][36];
  __shared__ __align__(16) float Kg[DZ][20];
  __shared__ __align__(16) float AKg[DZ][20];
  __shared__ __align__(16) float sa[T_LEN][DA];
  __shared__ float salpha[T_LEN*3];
  __shared__ __align__(16) float muv[DZ], mun[DZ], rv[DA], wv[DA];

  int tid = threadIdx.x;
  int b = blockIdx.x;

  for (int e = tid; e < T_LEN*DA; e += 256) (&sa[0][0])[e] = a[(size_t)b*T_LEN*DA + e];
  for (int e = tid; e < T_LEN*3; e += 256) salpha[e] = alpha[(size_t)b*T_LEN*3 + e];
  for (int e = tid; e < DZ*36; e += 256) (&Sg[0][0])[e] = 0.0f;
  __syncthreads();
  if (tid < DZ) { Sg[tid][tid] = 1.0f; muv[tid] = 0.0f; }

  const int i8 = tid >> 3, jA = tid & 7, jB = jA + 8, j4m = jA * 4;
  const int i16 = tid >> 4, j16 = tid & 15;
  const int iR = tid & 31, j4r = (tid >> 5) * 4;

  const float4* A4 = (const float4*)A;
  const float4* C4 = (const float4*)C;
  float4 pA0 = A4[(0*T_LEN + 1)*256 + tid];
  float4 pA1 = A4[(1*T_LEN + 1)*256 + tid];
  float4 pA2 = A4[(2*T_LEN + 1)*256 + tid];
  float4 pC0, pC1, pC2;
  if (tid < 128) {
    pC0 = C4[(0*T_LEN + 0)*128 + tid];
    pC1 = C4[(1*T_LEN + 0)*128 + tid];
    pC2 = C4[(2*T_LEN + 0)*128 + tid];
  }
  __syncthreads();

  #pragma unroll 1
  for (int t = 0; t < T_LEN; ++t) {
    int ta = (t < T_LEN-1) ? t+1 : t;
    float b10 = salpha[ta*3+0], b11 = salpha[ta*3+1], b12 = salpha[ta*3+2];
    float b00 = salpha[t*3+0],  b01 = salpha[t*3+1],  b02 = salpha[t*3+2];

    // ---- mix: Am (alpha[ta]), Cm (alpha[t]); issue next prefetch ----
    {
      float4 v;
      v.x = b10*pA0.x + b11*pA1.x + b12*pA2.x;
      v.y = b10*pA0.y + b11*pA1.y + b12*pA2.y;
      v.z = b10*pA0.z + b11*pA1.z + b12*pA2.z;
      v.w = b10*pA0.w + b11*pA1.w + b12*pA2.w;
      *(float4*)&Am[i8][j4m] = v;
      if (tid < 128) {
        float4 c;
        c.x = b00*pC0.x + b01*pC1.x + b02*pC2.x;
        c.y = b00*pC0.y + b01*pC1.y + b02*pC2.y;
        c.z = b00*pC0.z + b01*pC1.z + b02*pC2.z;
        c.w = b00*pC0.w + b01*pC1.w + b02*pC2.w;
        *(float4*)&Cm[tid>>3][(tid&7)*4] = c;
      }
      int tn  = (t+1 < T_LEN) ? t+1 : T_LEN-1;
      int tan = (tn < T_LEN-1) ? tn+1 : tn;
      pA0 = A4[(0*T_LEN + tan)*256 + tid];
      pA1 = A4[(1*T_LEN + tan)*256 + tid];
      pA2 = A4[(2*T_LEN + tan)*256 + tid];
      if (tid < 128) {
        pC0 = C4[(0*T_LEN + tn)*128 + tid];
        pC1 = C4[(1*T_LEN + tn)*128 + tid];
        pC2 = C4[(2*T_LEN + tn)*128 + tid];
      }
    }
    BAR();                                             // B0

    // ---- stage A: AmSg = Am*Sg ; N = Sg*Cm^T ; r = a_t - Cm*mu ----
    {
      float4 acc = make_float4(0.f,0.f,0.f,0.f);
      #pragma unroll
      for (int k4 = 0; k4 < 8; ++k4) {
        float4 am = *(const float4*)&Am[iR][4*k4];
        float4 s0 = *(const float4*)&Sg[4*k4+0][j4r];
        float4 s1 = *(const float4*)&Sg[4*k4+1][j4r];
        float4 s2 = *(const float4*)&Sg[4*k4+2][j4r];
        float4 s3 = *(const float4*)&Sg[4*k4+3][j4r];
        acc.x += am.x*s0.x + am.y*s1.x + am.z*s2.x + am.w*s3.x;
        acc.y += am.x*s0.y + am.y*s1.y + am.z*s2.y + am.w*s3.y;
        acc.z += am.x*s0.z + am.y*s1.z + am.z*s2.z + am.w*s3.z;
        acc.w += am.x*s0.w + am.y*s1.w + am.z*s2.w + am.w*s3.w;
      }
      *(float4*)&AmSg[iR][j4r] = acc;

      float accA = 0.0f, accB = 0.0f;
      #pragma unroll
      for (int k4 = 0; k4 < 8; ++k4) {
        float4 s  = *(const float4*)&Sg[i8][4*k4];
        float4 cA = *(const float4*)&Cm[jA][4*k4];
        float4 cB = *(const float4*)&Cm[jB][4*k4];
        accA += dot4(s,cA); accB += dot4(s,cB);
      }
      Nn[i8][jA] = accA; Nn[i8][jB] = accB;
      NnT[jA][i8] = accA; NnT[jB][i8] = accB;
      if (tid < DA) {
        float acc2 = sa[t][tid];
        #pragma unroll
        for (int k4 = 0; k4 < 8; ++k4)
          acc2 -= dot4(*(const float4*)&Cm[tid][4*k4], *(const float4*)&muv[4*k4]);
        rv[tid] = acc2;
      }
    }
    BAR();                                             // B1

    // ---- stage B: G = AmSg*Am^T ; M = AmSg*Cm^T ; Aug = [Cm*N + R | I] ----
    {
      float4 acc = make_float4(0.f,0.f,0.f,0.f);
      #pragma unroll
      for (int k4 = 0; k4 < 8; ++k4) {
        float4 p  = *(const float4*)&AmSg[iR][4*k4];
        float4 a0v = *(const float4*)&Am[j4r+0][4*k4];
        float4 a1v = *(const float4*)&Am[j4r+1][4*k4];
        float4 a2v = *(const float4*)&Am[j4r+2][4*k4];
        float4 a3v = *(const float4*)&Am[j4r+3][4*k4];
        acc.x += dot4(p,a0v); acc.y += dot4(p,a1v);
        acc.z += dot4(p,a2v); acc.w += dot4(p,a3v);
      }
      *(float4*)&Gm[iR][j4r] = acc;

      float mA = 0.0f, mB = 0.0f;
      #pragma unroll
      for (int k4 = 0; k4 < 8; ++k4) {
        float4 p  = *(const float4*)&AmSg[i8][4*k4];
        float4 cA = *(const float4*)&Cm[jA][4*k4];
        float4 cB = *(const float4*)&Cm[jB][4*k4];
        mA += dot4(p,cA); mB += dot4(p,cB);
      }
      Mm[i8][jA] = mA; Mm[i8][jB] = mB;

      float acc2 = 0.0f;
      #pragma unroll
      for (int k4 = 0; k4 < 8; ++k4) {
        float4 c = *(const float4*)&Cm[i16][4*k4];
        float4 n = *(const float4*)&NnT[j16][4*k4];
        acc2 += dot4(c,n);
      }
      Aug[i16][j16] = acc2 + ((i16 == j16) ? 0.01f : 0.0f);
      Aug[i16][16 + j16] = (i16 == j16) ? 1.0f : 0.0f;
    }
    BAR();                                             // B2

    // ---- GJ: wave-synchronous Gauss-Jordan + w = Sinv*r ----
    if (tid < 64) {
      int lane = tid;
      int r = lane >> 2, cb = lane & 3;
      float v[8];
      #pragma unroll
      for (int j = 0; j < 8; ++j) v[j] = Aug[r][cb*8 + j];
      #pragma unroll
      for (int p = 0; p < DA; ++p) {
        float App = __shfl(v[p & 7], (p << 2) | (p >> 3), 64);
        float f   = __shfl(v[p & 7], (lane & 60) | (p >> 3), 64);
        float prow[8];
        #pragma unroll
        for (int j = 0; j < 8; ++j) prow[j] = __shfl(v[j], (p << 2) | cb, 64);
        float pinv = 1.0f / App;
        if (r == p) {
          #pragma unroll
          for (int j = 0; j < 8; ++j) v[j] *= pinv;
        } else {
          float fp = f * pinv;
          #pragma unroll
          for (int j = 0; j < 8; ++j) v[j] -= fp * prow[j];
        }
      }
      float part = 0.0f;
      if (cb >= 2) {
        #pragma unroll
        for (int j = 0; j < 8; ++j) Aug[r][cb*8 + j] = v[j];
        int c0 = (cb - 2) * 8;
        float4 r0 = *(const float4*)&rv[c0];
        float4 r1 = *(const float4*)&rv[c0 + 4];
        part = v[0]*r0.x + v[1]*r0.y + v[2]*r0.z + v[3]*r0.w
             + v[4]*r1.x + v[5]*r1.y + v[6]*r1.z + v[7]*r1.w;
      }
      part += __shfl_xor(part, 1, 64);
      if (cb == 2) wv[r] = part;
    }
    BAR();                                             // B3

    // ---- stage D: Kg = N*Sinv ; AmK = M*Sinv ; mu+ = mu + N*w ; out ----
    {
      float kA = 0.0f, kB = 0.0f, qA = 0.0f, qB = 0.0f;
      #pragma unroll
      for (int k4 = 0; k4 < 4; ++k4) {
        float4 siA = *(const float4*)&Aug[jA][16 + 4*k4];
        float4 siB = *(const float4*)&Aug[jB][16 + 4*k4];
        float4 n   = *(const float4*)&Nn[i8][4*k4];
        float4 m   = *(const float4*)&Mm[i8][4*k4];
        kA += dot4(n,siA); kB += dot4(n,siB);
        qA += dot4(m,siA); qB += dot4(m,siB);
      }
      Kg[i8][jA] = kA; Kg[i8][jB] = kB;
      AKg[i8][jA] = qA; AKg[i8][jB] = qB;
      if (tid < DZ) {
        float mval = muv[tid];
        #pragma unroll
        for (int k4 = 0; k4 < 4; ++k4)
          mval += dot4(*(const float4*)&Nn[tid][4*k4], *(const float4*)&wv[4*k4]);
        mun[tid] = mval;
        out[((size_t)b*T_LEN + t)*DZ + tid] = mval;
      }
    }
    BAR();                                             // B4

    // ---- stage E: Sg' = G - AmK*M^T + Q ; mu_pred = Am*mu+ ----
    {
      float4 acc = *(const float4*)&Gm[iR][j4r];
      #pragma unroll
      for (int k4 = 0; k4 < 4; ++k4) {
        float4 kq = *(const float4*)&AKg[iR][4*k4];
        float4 m0 = *(const float4*)&Mm[j4r+0][4*k4];
        float4 m1 = *(const float4*)&Mm[j4r+1][4*k4];
        float4 m2 = *(const float4*)&Mm[j4r+2][4*k4];
        float4 m3 = *(const float4*)&Mm[j4r+3][4*k4];
        acc.x -= dot4(kq,m0); acc.y -= dot4(kq,m1);
        acc.z -= dot4(kq,m2); acc.w -= dot4(kq,m3);
      }
      int d = iR - j4r;
      if (d >= 0 && d < 4) (&acc.x)[d] += 0.01f;
      *(float4*)&Sg[iR][j4r] = acc;
      if (tid < DZ) {
        float mval = 0.0f;
        #pragma unroll
        for (int k4 = 0; k4 < 8; ++k4)
          mval += dot4(*(const float4*)&Am[tid][4*k4], *(const float4*)&mun[4*k4]);
        muv[tid] = mval;
      }
    }
    BAR();                                             // B5
  }
}

extern "C" void kernel_launch(void* const* d_in, const int* in_sizes, int n_in,
                              void* d_out, int out_size, void* d_ws, size_t ws_size,
                              hipStream_t stream) {
  const float* a    = (const float*)d_in[0];
  const float* A    = (const float*)d_in[1];
  const float* C    = (const float*)d_in[2];
  const float* a0   = (const float*)d_in[3];
  const float* Wih0 = (const float*)d_in[4];
  const float* Whh0 = (const float*)d_in[5];
  const float* bih0 = (const float*)d_in[6];
  const float* bhh0 = (const float*)d_in[7];
  const float* Wih1 = (const float*)d_in[8];
  const float* Whh1 = (const float*)d_in[9];
  const float* bih1 = (const float*)d_in[10];
  const float* bhh1 = (const float*)d_in[11];
  const float* Wlin = (const float*)d_in[12];
  const float* blin = (const float*)d_in[13];
  uint32_t* ws = (uint32_t*)d_ws;
  float* alpha = (float*)(ws + 103424);
  float* out = (float*)d_out;

  prep_kernel<<<404, 256, 0, stream>>>(Wih0, Whh0, bih0, bhh0, Wih1, Whh1, bih1, bhh1, ws);
  lstm_kernel<<<256, 512, 0, stream>>>(a, a0, ws, Wlin, blin, alpha);
  kalman_kernel<<<512, 256, 0, stream>>>(a, A, C, alpha, out);
}

// Round 3
// 1247.321 us; speedup vs baseline: 1.2547x; 1.1162x over previous
//
#include <hip/hip_runtime.h>
#include <hip/hip_fp16.h>
#include <cstdint>

#define T_LEN 128
#define DA    16
#define DZ    32
#define HH    128

__device__ __forceinline__ float sigm(float x){ return 1.0f/(1.0f + __expf(-x)); }
__device__ __forceinline__ float tanh_f(float x){ return 1.0f - 2.0f/(__expf(2.0f*x)+1.0f); }
__device__ __forceinline__ float dot4(float4 a, float4 b){ return a.x*b.x + a.y*b.y + a.z*b.z + a.w*b.w; }

typedef _Float16 h2v __attribute__((ext_vector_type(2)));
__device__ __forceinline__ float fdot2(uint32_t w, uint32_t h, float acc){
  union{uint32_t u; h2v v;} a, b; a.u = w; b.u = h;
  return __builtin_amdgcn_fdot2(a.v, b.v, acc, false);
}
__device__ __forceinline__ uint32_t packh2(float x, float y){
  return (uint32_t)__half_as_ushort(__float2half(x)) |
         ((uint32_t)__half_as_ushort(__float2half(y)) << 16);
}

// LDS-only barrier: drain LDS pipe (write visibility), then raw s_barrier.
// Does NOT drain vmcnt, so global prefetch loads stay in flight.
#define BAR() do { asm volatile("s_waitcnt lgkmcnt(0)" ::: "memory"); \
                   __builtin_amdgcn_s_barrier(); } while (0)

// ws layout (32-bit words):
//   [0,4096)         Wih0h fp16-pairs: word idx (m*512+g)*4+q, m<2, q<4 -> w[g][8m+2q..+1]
//   [4096,36864)     Whh0h: m<16
//   [36864,69632)    Wih1h: m<16
//   [69632,102400)   Whh1h: m<16
//   [102400,102912)  b0 = bih0+bhh0 (f32)
//   [102912,103424)  b1 = bih1+bhh1 (f32)
//   [103424,300032)  alpha (512,128,3) f32

__global__ void prep_kernel(const float* __restrict__ Wih0, const float* __restrict__ Whh0,
                            const float* __restrict__ bih0, const float* __restrict__ bhh0,
                            const float* __restrict__ Wih1, const float* __restrict__ Whh1,
                            const float* __restrict__ bih1, const float* __restrict__ bhh1,
                            uint32_t* __restrict__ ws) {
  int idx = blockIdx.x*256 + threadIdx.x;
  if (idx < 4096) {
    int q = idx & 3, g = (idx >> 2) & 511, m = idx >> 11;
    int k0 = 8*m + 2*q;
    ws[idx] = packh2(Wih0[g*DA + k0], Wih0[g*DA + k0 + 1]);
  } else if (idx < 36864) {
    int f = idx - 4096;
    int q = f & 3, g = (f >> 2) & 511, m = f >> 11;
    int k0 = 8*m + 2*q;
    ws[idx] = packh2(Whh0[g*HH + k0], Whh0[g*HH + k0 + 1]);
  } else if (idx < 69632) {
    int f = idx - 36864;
    int q = f & 3, g = (f >> 2) & 511, m = f >> 11;
    int k0 = 8*m + 2*q;
    ws[idx] = packh2(Wih1[g*HH + k0], Wih1[g*HH + k0 + 1]);
  } else if (idx < 102400) {
    int f = idx - 69632;
    int q = f & 3, g = (f >> 2) & 511, m = f >> 11;
    int k0 = 8*m + 2*q;
    ws[idx] = packh2(Whh1[g*HH + k0], Whh1[g*HH + k0 + 1]);
  } else if (idx < 102912) {
    int j = idx - 102400;
    ((float*)ws)[idx] = bih0[j] + bhh0[j];
  } else if (idx < 103424) {
    int j = idx - 102912;
    ((float*)ws)[idx] = bih1[j] + bhh1[j];
  }
}

// Persistent 2-layer LSTM (unchanged: register-resident weights + dual-row).
__global__ __launch_bounds__(512, 2) void lstm_kernel(
    const float* __restrict__ a, const float* __restrict__ a0,
    const uint32_t* __restrict__ wsw, const float* __restrict__ Wlin,
    const float* __restrict__ blin, float* __restrict__ alpha_out) {
  const uint4* Wih0p = (const uint4*)(wsw);
  const uint4* Whh0p = (const uint4*)(wsw + 4096);
  const uint4* Wih1p = (const uint4*)(wsw + 36864);
  const uint4* Whh1p = (const uint4*)(wsw + 69632);
  const float* b0v = (const float*)(wsw + 102400);
  const float* b1v = (const float*)(wsw + 102912);

  __shared__ __align__(16) uint32_t sxh[2][T_LEN][8];
  __shared__ __align__(16) uint32_t sh0h[2][64];
  __shared__ __align__(16) uint32_t sh1h[2][64];
  __shared__ float gates[2][4*HH];

  int tid = threadIdx.x;
  int lane = tid & 63;
  int wv = tid >> 6;
  int bb = blockIdx.x * 2;

  uint4 wi0[2], wh0[16], wi1[16], wh1[16];
  #pragma unroll
  for (int m = 0; m < 2; ++m)  wi0[m] = Wih0p[m*512 + tid];
  #pragma unroll
  for (int m = 0; m < 16; ++m) wh0[m] = Whh0p[m*512 + tid];
  #pragma unroll
  for (int m = 0; m < 16; ++m) wi1[m] = Wih1p[m*512 + tid];
  #pragma unroll
  for (int m = 0; m < 16; ++m) wh1[m] = Whh1p[m*512 + tid];
  float bi0 = b0v[tid], bi1 = b1v[tid];

  for (int i = tid; i < 2*T_LEN*8; i += 512) {
    int r = i / (T_LEN*8), rem = i % (T_LEN*8), t = rem >> 3, p = rem & 7;
    float x0, x1;
    if (t == 0) { x0 = a0[2*p]; x1 = a0[2*p+1]; }
    else {
      const float* src = a + ((size_t)(bb + r)*T_LEN + (t-1))*DA;
      x0 = src[2*p]; x1 = src[2*p+1];
    }
    sxh[r][t][p] = packh2(x0, x1);
  }
  float wl00 = Wlin[0*HH + 2*lane], wl01 = Wlin[0*HH + 2*lane+1];
  float wl10 = Wlin[1*HH + 2*lane], wl11 = Wlin[1*HH + 2*lane+1];
  float wl20 = Wlin[2*HH + 2*lane], wl21 = Wlin[2*HH + 2*lane+1];
  float bl0 = blin[0], bl1 = blin[1], bl2 = blin[2];
  float c00 = 0.f, c01 = 0.f, c10 = 0.f, c11 = 0.f;
  if (tid < 128) { sh0h[wv][lane] = 0u; sh1h[wv][lane] = 0u; }
  __syncthreads();

  #pragma unroll 1
  for (int t = 0; t < T_LEN; ++t) {
    {
      float g0a = bi0, g0b = 0.f, g1a = bi0, g1b = 0.f;
      uint4 xA0 = *(const uint4*)&sxh[0][t][0];
      uint4 xA1 = *(const uint4*)&sxh[0][t][4];
      uint4 xB0 = *(const uint4*)&sxh[1][t][0];
      uint4 xB1 = *(const uint4*)&sxh[1][t][4];
      g0a = fdot2(wi0[0].x, xA0.x, g0a); g0b = fdot2(wi0[0].y, xA0.y, g0b);
      g0a = fdot2(wi0[0].z, xA0.z, g0a); g0b = fdot2(wi0[0].w, xA0.w, g0b);
      g0a = fdot2(wi0[1].x, xA1.x, g0a); g0b = fdot2(wi0[1].y, xA1.y, g0b);
      g0a = fdot2(wi0[1].z, xA1.z, g0a); g0b = fdot2(wi0[1].w, xA1.w, g0b);
      g1a = fdot2(wi0[0].x, xB0.x, g1a); g1b = fdot2(wi0[0].y, xB0.y, g1b);
      g1a = fdot2(wi0[0].z, xB0.z, g1a); g1b = fdot2(wi0[0].w, xB0.w, g1b);
      g1a = fdot2(wi0[1].x, xB1.x, g1a); g1b = fdot2(wi0[1].y, xB1.y, g1b);
      g1a = fdot2(wi0[1].z, xB1.z, g1a); g1b = fdot2(wi0[1].w, xB1.w, g1b);
      #pragma unroll
      for (int m = 0; m < 16; ++m) {
        uint4 w = wh0[m];
        uint4 hA = *(const uint4*)&sh0h[0][4*m];
        uint4 hB = *(const uint4*)&sh0h[1][4*m];
        g0a = fdot2(w.x, hA.x, g0a); g0b = fdot2(w.y, hA.y, g0b);
        g0a = fdot2(w.z, hA.z, g0a); g0b = fdot2(w.w, hA.w, g0b);
        g1a = fdot2(w.x, hB.x, g1a); g1b = fdot2(w.y, hB.y, g1b);
        g1a = fdot2(w.z, hB.z, g1a); g1b = fdot2(w.w, hB.w, g1b);
      }
      gates[0][tid] = g0a + g0b;
      gates[1][tid] = g1a + g1b;
    }
    __syncthreads();                                   // B1
    if (tid < 128) {
      int j0 = 2*lane, j1 = j0 + 1;
      float i0 = gates[wv][j0],      f0 = gates[wv][j0+HH],
            q0 = gates[wv][j0+2*HH], o0 = gates[wv][j0+3*HH];
      c00 = sigm(f0)*c00 + sigm(i0)*tanh_f(q0);
      float hv0 = sigm(o0)*tanh_f(c00);
      float i1 = gates[wv][j1],      f1 = gates[wv][j1+HH],
            q1 = gates[wv][j1+2*HH], o1 = gates[wv][j1+3*HH];
      c01 = sigm(f1)*c01 + sigm(i1)*tanh_f(q1);
      float hv1 = sigm(o1)*tanh_f(c01);
      sh0h[wv][lane] = packh2(hv0, hv1);
    }
    __syncthreads();                                   // B2
    {
      float g0a = bi1, g0b = 0.f, g1a = bi1, g1b = 0.f;
      #pragma unroll
      for (int m = 0; m < 16; ++m) {
        uint4 w = wi1[m];
        uint4 hA = *(const uint4*)&sh0h[0][4*m];
        uint4 hB = *(const uint4*)&sh0h[1][4*m];
        g0a = fdot2(w.x, hA.x, g0a); g0b = fdot2(w.y, hA.y, g0b);
        g0a = fdot2(w.z, hA.z, g0a); g0b = fdot2(w.w, hA.w, g0b);
        g1a = fdot2(w.x, hB.x, g1a); g1b = fdot2(w.y, hB.y, g1b);
        g1a = fdot2(w.z, hB.z, g1a); g1b = fdot2(w.w, hB.w, g1b);
      }
      #pragma unroll
      for (int m = 0; m < 16; ++m) {
        uint4 w = wh1[m];
        uint4 hA = *(const uint4*)&sh1h[0][4*m];
        uint4 hB = *(const uint4*)&sh1h[1][4*m];
        g0a = fdot2(w.x, hA.x, g0a); g0b = fdot2(w.y, hA.y, g0b);
        g0a = fdot2(w.z, hA.z, g0a); g0b = fdot2(w.w, hA.w, g0b);
        g1a = fdot2(w.x, hB.x, g1a); g1b = fdot2(w.y, hB.y, g1b);
        g1a = fdot2(w.w, hB.w, g1b); g1a = fdot2(w.z, hB.z, g1a);
      }
      gates[0][tid] = g0a + g0b;
      gates[1][tid] = g1a + g1b;
    }
    __syncthreads();                                   // B3
    float hv0 = 0.f, hv1 = 0.f;
    if (tid < 128) {
      int j0 = 2*lane, j1 = j0 + 1;
      float i0 = gates[wv][j0],      f0 = gates[wv][j0+HH],
            q0 = gates[wv][j0+2*HH], o0 = gates[wv][j0+3*HH];
      c10 = sigm(f0)*c10 + sigm(i0)*tanh_f(q0);
      hv0 = sigm(o0)*tanh_f(c10);
      float i1 = gates[wv][j1],      f1 = gates[wv][j1+HH],
            q1 = gates[wv][j1+2*HH], o1 = gates[wv][j1+3*HH];
      c11 = sigm(f1)*c11 + sigm(i1)*tanh_f(q1);
      hv1 = sigm(o1)*tanh_f(c11);
      sh1h[wv][lane] = packh2(hv0, hv1);
    }
    __syncthreads();                                   // B4
    if (tid < 128) {
      float p0 = hv0*wl00 + hv1*wl01;
      float p1 = hv0*wl10 + hv1*wl11;
      float p2 = hv0*wl20 + hv1*wl21;
      #pragma unroll
      for (int off = 32; off > 0; off >>= 1) {
        p0 += __shfl_down(p0, off); p1 += __shfl_down(p1, off); p2 += __shfl_down(p2, off);
      }
      if (lane == 0) {
        float l0 = p0 + bl0, l1 = p1 + bl1, l2 = p2 + bl2;
        float mx = fmaxf(l0, fmaxf(l1, l2));
        float e0=__expf(l0-mx), e1=__expf(l1-mx), e2=__expf(l2-mx);
        float inv = 1.0f/(e0+e1+e2);
        float* dst = alpha_out + (((size_t)(bb+wv))*T_LEN + t)*3;
        dst[0]=e0*inv; dst[1]=e1*inv; dst[2]=e2*inv;
      }
    }
  }
}

// Kalman scan v7 = v4 (the proven 851us structure: 512 blocks x 256 thr,
// conflict-free k-row matmuls, register prefetch) + three surgical cuts:
//  (1) GJ static broadcasts off the DS pipe: App via v_readlane (SALU),
//      f via v_mov_dpp quad_perm (VALU) -- saves 32 bpermutes/step and
//      shortens the 16-pivot serial chain. prow stays __shfl.
//  (2) BAR() lgkmcnt-only barriers in the t-loop (prefetch stays in flight).
//  (3) serial vector work (r, mu+, mu_pred) moved off wave 0 (the GJ wave)
//      to waves 3/1/2 respectively.
__global__ __launch_bounds__(256) void kalman_kernel(
    const float* __restrict__ a, const float* __restrict__ A,
    const float* __restrict__ C, const float* __restrict__ alpha,
    float* __restrict__ out) {
  __shared__ __align__(16) float Sg[DZ][36];
  __shared__ __align__(16) float Am[DZ][36];
  __shared__ __align__(16) float AmT[DZ][36];
  __shared__ __align__(16) float Cm[DA][36];
  __shared__ __align__(16) float Nn[DZ][20];
  __shared__ __align__(16) float NnT[DA][36];
  __shared__ __align__(16) float Aug[DA][36];
  __shared__ __align__(16) float Kg[DZ][20];
  __shared__ __align__(16) float Sp2[DZ][36];
  __shared__ __align__(16) float T2m[DZ][36];
  __shared__ __align__(16) float sa[T_LEN][DA];
  __shared__ float salpha[T_LEN*3];
  __shared__ __align__(16) float muv[DZ], mun[DZ], rv[DA];

  int tid = threadIdx.x;
  int b = blockIdx.x;

  for (int e = tid; e < T_LEN*DA; e += 256) (&sa[0][0])[e] = a[(size_t)b*T_LEN*DA + e];
  for (int e = tid; e < T_LEN*3; e += 256) salpha[e] = alpha[(size_t)b*T_LEN*3 + e];
  for (int e = tid; e < DZ*36; e += 256) (&Sg[0][0])[e] = 0.0f;
  __syncthreads();
  if (tid < DZ) { Sg[tid][tid] = 1.0f; muv[tid] = 0.0f; }

  const int i8 = tid >> 3, jA = tid & 7, jB = jA + 8, j4m = jA * 4;
  const int i16 = tid >> 4, j16 = tid & 15;
  const int iR = tid & 31, j4r = (tid >> 5) * 4;

  const float4* A4 = (const float4*)A;
  const float4* C4 = (const float4*)C;
  float4 pA0 = A4[(0*T_LEN + 1)*256 + tid];
  float4 pA1 = A4[(1*T_LEN + 1)*256 + tid];
  float4 pA2 = A4[(2*T_LEN + 1)*256 + tid];
  float4 pC0, pC1, pC2;
  if (tid < 128) {
    pC0 = C4[(0*T_LEN + 0)*128 + tid];
    pC1 = C4[(1*T_LEN + 0)*128 + tid];
    pC2 = C4[(2*T_LEN + 0)*128 + tid];
  }
  __syncthreads();

  #pragma unroll 1
  for (int t = 0; t < T_LEN; ++t) {
    int ta = (t < T_LEN-1) ? t+1 : t;
    float b10 = salpha[ta*3+0], b11 = salpha[ta*3+1], b12 = salpha[ta*3+2];
    float b00 = salpha[t*3+0],  b01 = salpha[t*3+1],  b02 = salpha[t*3+2];

    {
      float4 v;
      v.x = b10*pA0.x + b11*pA1.x + b12*pA2.x;
      v.y = b10*pA0.y + b11*pA1.y + b12*pA2.y;
      v.z = b10*pA0.z + b11*pA1.z + b12*pA2.z;
      v.w = b10*pA0.w + b11*pA1.w + b12*pA2.w;
      *(float4*)&Am[i8][j4m] = v;
      AmT[j4m+0][i8] = v.x; AmT[j4m+1][i8] = v.y;
      AmT[j4m+2][i8] = v.z; AmT[j4m+3][i8] = v.w;
      if (tid < 128) {
        float4 c;
        c.x = b00*pC0.x + b01*pC1.x + b02*pC2.x;
        c.y = b00*pC0.y + b01*pC1.y + b02*pC2.y;
        c.z = b00*pC0.z + b01*pC1.z + b02*pC2.z;
        c.w = b00*pC0.w + b01*pC1.w + b02*pC2.w;
        *(float4*)&Cm[tid>>3][(tid&7)*4] = c;
      }
      int tn  = (t+1 < T_LEN) ? t+1 : T_LEN-1;
      int tan = (tn < T_LEN-1) ? tn+1 : tn;
      pA0 = A4[(0*T_LEN + tan)*256 + tid];
      pA1 = A4[(1*T_LEN + tan)*256 + tid];
      pA2 = A4[(2*T_LEN + tan)*256 + tid];
      if (tid < 128) {
        pC0 = C4[(0*T_LEN + tn)*128 + tid];
        pC1 = C4[(1*T_LEN + tn)*128 + tid];
        pC2 = C4[(2*T_LEN + tn)*128 + tid];
      }
    }
    BAR();

    {
      float accA = 0.0f, accB = 0.0f;
      #pragma unroll
      for (int k4 = 0; k4 < 8; ++k4) {
        float4 s  = *(const float4*)&Sg[i8][k4*4];
        float4 cA = *(const float4*)&Cm[jA][k4*4];
        float4 cB = *(const float4*)&Cm[jB][k4*4];
        accA += dot4(s,cA); accB += dot4(s,cB);
      }
      Nn[i8][jA] = accA; Nn[i8][jB] = accB;
      NnT[jA][i8] = accA; NnT[jB][i8] = accB;
      if (tid >= 192 && tid < 192 + DA) {
        int j = tid - 192;
        float acc = sa[t][j];
        #pragma unroll
        for (int k4 = 0; k4 < 8; ++k4)
          acc -= dot4(*(const float4*)&Cm[j][k4*4], *(const float4*)&muv[k4*4]);
        rv[j] = acc;
      }
    }
    BAR();

    {
      float acc = 0.0f;
      #pragma unroll
      for (int k4 = 0; k4 < 8; ++k4) {
        float4 c = *(const float4*)&Cm[i16][k4*4];
        float4 n = *(const float4*)&NnT[j16][k4*4];
        acc += dot4(c,n);
      }
      Aug[i16][j16] = acc + ((i16 == j16) ? 0.01f : 0.0f);
      Aug[i16][16 + j16] = (i16 == j16) ? 1.0f : 0.0f;
    }
    BAR();

    if (tid < 64) {
      int lane = tid;
      int r = lane >> 2, cb = lane & 3;
      float v[8];
      #pragma unroll
      for (int j = 0; j < 8; ++j) v[j] = Aug[r][cb*8 + j];
      // Per-pivot: App via readlane (static lane), f via DPP quad_perm
      // (broadcast element p>>3 within each quad), prow via __shfl.
      #define GJ_PIVOT(P, CTRL)                                                \
      {                                                                        \
        float App = __int_as_float(__builtin_amdgcn_readlane(                  \
                      __float_as_int(v[(P) & 7]), ((P) << 2) | ((P) >> 3)));   \
        float fv  = __int_as_float(__builtin_amdgcn_mov_dpp(                   \
                      __float_as_int(v[(P) & 7]), (CTRL), 0xf, 0xf, true));    \
        float prow[8];                                                         \
        _Pragma("unroll")                                                      \
        for (int j = 0; j < 8; ++j) prow[j] = __shfl(v[j], ((P) << 2) | cb, 64); \
        float pinv = 1.0f / App;                                               \
        if (r == (P)) {                                                        \
          _Pragma("unroll")                                                    \
          for (int j = 0; j < 8; ++j) v[j] *= pinv;                            \
        } else {                                                               \
          float fp = fv * pinv;                                                \
          _Pragma("unroll")                                                    \
          for (int j = 0; j < 8; ++j) v[j] -= fp * prow[j];                    \
        }                                                                      \
      }
      GJ_PIVOT(0, 0x00)  GJ_PIVOT(1, 0x00)  GJ_PIVOT(2, 0x00)  GJ_PIVOT(3, 0x00)
      GJ_PIVOT(4, 0x00)  GJ_PIVOT(5, 0x00)  GJ_PIVOT(6, 0x00)  GJ_PIVOT(7, 0x00)
      GJ_PIVOT(8, 0x55)  GJ_PIVOT(9, 0x55)  GJ_PIVOT(10, 0x55) GJ_PIVOT(11, 0x55)
      GJ_PIVOT(12, 0x55) GJ_PIVOT(13, 0x55) GJ_PIVOT(14, 0x55) GJ_PIVOT(15, 0x55)
      #undef GJ_PIVOT
      if (cb >= 2) {
        #pragma unroll
        for (int j = 0; j < 8; ++j) Aug[r][cb*8 + j] = v[j];
      }
    }
    BAR();

    {
      float accA = 0.0f, accB = 0.0f;
      #pragma unroll
      for (int k4 = 0; k4 < 4; ++k4) {
        float4 n  = *(const float4*)&Nn[i8][k4*4];
        float4 sA = *(const float4*)&Aug[jA][16 + k4*4];
        float4 sB = *(const float4*)&Aug[jB][16 + k4*4];
        accA += dot4(n,sA); accB += dot4(n,sB);
      }
      Kg[i8][jA] = accA; Kg[i8][jB] = accB;
    }
    BAR();

    if (tid >= 64 && tid < 64 + DZ) {
      int j = tid - 64;
      float m = muv[j];
      #pragma unroll
      for (int k4 = 0; k4 < 4; ++k4)
        m += dot4(*(const float4*)&Kg[j][k4*4], *(const float4*)&rv[k4*4]);
      mun[j] = m;
      out[((size_t)b*T_LEN + t)*DZ + j] = m;
    }
    {
      float4 acc = *(const float4*)&Sg[iR][j4r];
      #pragma unroll
      for (int k4 = 0; k4 < 4; ++k4) {
        float4 kv = *(const float4*)&Kg[iR][k4*4];
        float4 n0 = *(const float4*)&NnT[4*k4+0][j4r];
        float4 n1 = *(const float4*)&NnT[4*k4+1][j4r];
        float4 n2 = *(const float4*)&NnT[4*k4+2][j4r];
        float4 n3 = *(const float4*)&NnT[4*k4+3][j4r];
        acc.x -= kv.x*n0.x + kv.y*n1.x + kv.z*n2.x + kv.w*n3.x;
        acc.y -= kv.x*n0.y + kv.y*n1.y + kv.z*n2.y + kv.w*n3.y;
        acc.z -= kv.x*n0.z + kv.y*n1.z + kv.z*n2.z + kv.w*n3.z;
        acc.w -= kv.x*n0.w + kv.y*n1.w + kv.z*n2.w + kv.w*n3.w;
      }
      *(float4*)&Sp2[iR][j4r] = acc;
    }
    BAR();

    {
      float4 acc = make_float4(0.f,0.f,0.f,0.f);
      #pragma unroll
      for (int k4 = 0; k4 < 8; ++k4) {
        float4 av = *(const float4*)&Am[iR][k4*4];
        float4 b0 = *(const float4*)&Sp2[4*k4+0][j4r];
        float4 b1 = *(const float4*)&Sp2[4*k4+1][j4r];
        float4 b2 = *(const float4*)&Sp2[4*k4+2][j4r];
        float4 b3 = *(const float4*)&Sp2[4*k4+3][j4r];
        acc.x += av.x*b0.x + av.y*b1.x + av.z*b2.x + av.w*b3.x;
        acc.y += av.x*b0.y + av.y*b1.y + av.z*b2.y + av.w*b3.y;
        acc.z += av.x*b0.z + av.y*b1.z + av.z*b2.z + av.w*b3.z;
        acc.w += av.x*b0.w + av.y*b1.w + av.z*b2.w + av.w*b3.w;
      }
      *(float4*)&T2m[iR][j4r] = acc;
    }
    BAR();

    {
      float4 acc = make_float4(0.f,0.f,0.f,0.f);
      #pragma unroll
      for (int k4 = 0; k4 < 8; ++k4) {
        float4 tv = *(const float4*)&T2m[iR][k4*4];
        float4 b0 = *(const float4*)&AmT[4*k4+0][j4r];
        float4 b1 = *(const float4*)&AmT[4*k4+1][j4r];
        float4 b2 = *(const float4*)&AmT[4*k4+2][j4r];
        float4 b3 = *(const float4*)&AmT[4*k4+3][j4r];
        acc.x += tv.x*b0.x + tv.y*b1.x + tv.z*b2.x + tv.w*b3.x;
        acc.y += tv.x*b0.y + tv.y*b1.y + tv.z*b2.y + tv.w*b3.y;
        acc.z += tv.x*b0.z + tv.y*b1.z + tv.z*b2.z + tv.w*b3.z;
        acc.w += tv.x*b0.w + tv.y*b1.w + tv.z*b2.w + tv.w*b3.w;
      }
      int d = iR - j4r;
      if (d >= 0 && d < 4) (&acc.x)[d] += 0.01f;
      *(float4*)&Sg[iR][j4r] = acc;
    }
    if (tid >= 128 && tid < 128 + DZ) {
      int j = tid - 128;
      float m = 0.0f;
      #pragma unroll
      for (int k4 = 0; k4 < 8; ++k4)
        m += dot4(*(const float4*)&Am[j][k4*4], *(const float4*)&mun[k4*4]);
      muv[j] = m;
    }
    BAR();
  }
}

extern "C" void kernel_launch(void* const* d_in, const int* in_sizes, int n_in,
                              void* d_out, int out_size, void* d_ws, size_t ws_size,
                              hipStream_t stream) {
  const float* a    = (const float*)d_in[0];
  const float* A    = (const float*)d_in[1];
  const float* C    = (const float*)d_in[2];
  const float* a0   = (const float*)d_in[3];
  const float* Wih0 = (const float*)d_in[4];
  const float* Whh0 = (const float*)d_in[5];
  const float* bih0 = (const float*)d_in[6];
  const float* bhh0 = (const float*)d_in[7];
  const float* Wih1 = (const float*)d_in[8];
  const float* Whh1 = (const float*)d_in[9];
  const float* bih1 = (const float*)d_in[10];
  const float* bhh1 = (const float*)d_in[11];
  const float* Wlin = (const float*)d_in[12];
  const float* blin = (const float*)d_in[13];
  uint32_t* ws = (uint32_t*)d_ws;
  float* alpha = (float*)(ws + 103424);
  float* out = (float*)d_out;

  prep_kernel<<<404, 256, 0, stream>>>(Wih0, Whh0, bih0, bhh0, Wih1, Whh1, bih1, bhh1, ws);
  lstm_kernel<<<256, 512, 0, stream>>>(a, a0, ws, Wlin, blin, alpha);
  kalman_kernel<<<512, 256, 0, stream>>>(a, A, C, alpha, out);
}